// Round 12
// baseline (1302.889 us; speedup 1.0000x reference)
//
#include <hip/hip_runtime.h>
#include <math.h>

// SchNet forward, MI355X. Round 12: TK 32->64 (half the barriers).
// r11 showed the node GEMM flat at 63us while VALUBusy fell 53->48% and no
// pipe >50% at 41% occupancy -> per-chunk barrier chain is the cost unit
// (19 iterations of barrier->ds_read->MFMA->barrier). TK=64: 10 chunks,
// 24 MFMAs/barrier. Needs K%64==0 -> HP 608->640 (2560B = 40 sectors, still
// sector-aligned). LDS 20->37KB, lb(256,4) = 4 blocks/CU. int4-only staging
// loads/stores (guaranteed b128).
// Stack: clamped staging + pointer increments (r11), segment pool + batched
// tab GEMMs (r7/8), packed bf16 hi/lo everywhere (r5), XCD swizzle (r4),
// CSR gather (r2), filter-table + lerp (r1; absmax 2.4e-4 vs 1.44e-3).

#define N_ATOMS 10000
#define E_EDGES 64000
#define B_MOLS  128
#define H_DIM   600
#define HP      640            // padded leading dim (640*4B = 40 sectors, K%64==0)
#define G_DIM   50
#define L_LAYERS 6
#define M_TAB   1024
#define DMAX    8.67f
#define LOG2C   0.69314718056f

#define TM 64
#define TN 64
#define TK 64
#define SA 72          // LDS row stride in shorts (144B rows, 16B-aligned)

typedef __attribute__((ext_vector_type(8))) short bf16x8;
typedef __attribute__((ext_vector_type(4))) float f32x4;

__device__ __forceinline__ float sspf(float x) {
    return fmaxf(x, 0.0f) + log1pf(expf(-fabsf(x))) - LOG2C;
}
__device__ __forceinline__ short f2bf(float x) {
    unsigned u = __float_as_uint(x);
    unsigned r = (u + 0x7FFF + ((u >> 16) & 1)) >> 16;   // RNE
    return (short)r;
}
__device__ __forceinline__ float bf2f(short h) {
    return __uint_as_float(((unsigned)(unsigned short)h) << 16);
}
__device__ __forceinline__ int packsplit(float x) {
    short hi = f2bf(x);
    short lo = f2bf(x - bf2f(hi));
    return ((int)hi << 16) | ((int)lo & 0xffff);
}
__device__ __forceinline__ float unpackf(int p) {
    float fh = __uint_as_float((unsigned)p & 0xffff0000u);
    float fl = __uint_as_float(((unsigned)p) << 16);
    return fh + fl;
}

// unpack int4 (4 packed hi|lo) -> hi short4 / lo short4
__device__ __forceinline__ void unpack4(const int4& p, short4& vh, short4& vl) {
    vh = make_short4((short)(p.x >> 16), (short)(p.y >> 16),
                     (short)(p.z >> 16), (short)(p.w >> 16));
    vl = make_short4((short)p.x, (short)p.y, (short)p.z, (short)p.w);
}

// ---------------------------------------------------------------- MFMA GEMM
// outP = packsplit(op(A @ B + bias [+ unpack(outP)])). A: packed int [Ma][lda]
// (zero-padded cols). B: TRANSPOSED pre-split bf16 hi/lo [Nc][ldb] (zero-
// padded k). K % 64 == 0. Output ld = HP, pad cols 0. 1D grid, XCD swizzle.
// Staging rows clamped once; OOB contributions masked by the epilogue.
template<bool BIAS, bool ACT, bool ACCUM>
__global__ __launch_bounds__(256, 4)
void gemm_mfma(const int* __restrict__ A, int lda,
               const short* __restrict__ Bh, const short* __restrict__ Bl, int ldb,
               const float* __restrict__ bias,
               int* __restrict__ outP,
               int Ma, int K, int Nc)
{
    const int NT = (Nc + TN - 1) / TN;
    const int f = blockIdx.x;
    const int xcd = f & 7, s = f >> 3;
    const int n0 = (s % NT) * TN;
    const int m0 = (xcd + 8 * (s / NT)) * TM;
    if (m0 >= Ma) return;

    __shared__ __align__(16) short As[2][TM * SA];
    __shared__ __align__(16) short Bs[2][TN * SA];

    const int tid = threadIdx.x;
    const int lane = tid & 63, wid = tid >> 6;
    const int wm = (wid >> 1) * 32, wn = (wid & 1) * 32;
    const int l15 = lane & 15, quad = lane >> 4;
    const int srow = tid >> 2;          // 0..63
    const int skk  = (tid & 3) << 4;    // 0,16,32,48 (shorts / ints)

    const int gm = min(m0 + srow, Ma - 1);
    const int gn = min(n0 + srow, Nc - 1);
    const int*   aPtr  = A  + (size_t)gm * lda + skk;
    const short* bPtrH = Bh + (size_t)gn * ldb + skk;
    const short* bPtrL = Bl + (size_t)gn * ldb + skk;

    f32x4 acc[2][2];
    #pragma unroll
    for (int i = 0; i < 2; ++i)
        #pragma unroll
        for (int j = 0; j < 2; ++j)
            acc[i][j] = (f32x4){0.f, 0.f, 0.f, 0.f};

    int4 ra[4];                 // 16 packed A ints (16 k)
    int4 rbh0, rbh1, rbl0, rbl1;   // 16 shorts per plane

    // prefetch chunk 0
    #pragma unroll
    for (int j = 0; j < 4; ++j) ra[j] = *(const int4*)(aPtr + 4 * j);
    rbh0 = *(const int4*)bPtrH; rbh1 = *(const int4*)(bPtrH + 8);
    rbl0 = *(const int4*)bPtrL; rbl1 = *(const int4*)(bPtrL + 8);
    aPtr += TK; bPtrH += TK; bPtrL += TK;

    for (int k0 = 0; k0 < K; k0 += TK) {
        {
            #pragma unroll
            for (int j = 0; j < 4; ++j) {
                short4 vh, vl;
                unpack4(ra[j], vh, vl);
                *(short4*)&As[0][srow * SA + skk + 4 * j] = vh;
                *(short4*)&As[1][srow * SA + skk + 4 * j] = vl;
            }
            *(int4*)&Bs[0][srow * SA + skk]     = rbh0;
            *(int4*)&Bs[0][srow * SA + skk + 8] = rbh1;
            *(int4*)&Bs[1][srow * SA + skk]     = rbl0;
            *(int4*)&Bs[1][srow * SA + skk + 8] = rbl1;
        }
        __syncthreads();

        if (k0 + TK < K) {
            #pragma unroll
            for (int j = 0; j < 4; ++j) ra[j] = *(const int4*)(aPtr + 4 * j);
            rbh0 = *(const int4*)bPtrH; rbh1 = *(const int4*)(bPtrH + 8);
            rbl0 = *(const int4*)bPtrL; rbl1 = *(const int4*)(bPtrL + 8);
            aPtr += TK; bPtrH += TK; bPtrL += TK;
        }

        #pragma unroll
        for (int kk = 0; kk < 2; ++kk) {
            bf16x8 a_h[2], a_l[2], b_h[2], b_l[2];
            #pragma unroll
            for (int mi = 0; mi < 2; ++mi) {
                int off = (wm + mi * 16 + l15) * SA + kk * 32 + quad * 8;
                a_h[mi] = *(const bf16x8*)&As[0][off];
                a_l[mi] = *(const bf16x8*)&As[1][off];
            }
            #pragma unroll
            for (int ni = 0; ni < 2; ++ni) {
                int off = (wn + ni * 16 + l15) * SA + kk * 32 + quad * 8;
                b_h[ni] = *(const bf16x8*)&Bs[0][off];
                b_l[ni] = *(const bf16x8*)&Bs[1][off];
            }
            #pragma unroll
            for (int mi = 0; mi < 2; ++mi)
                #pragma unroll
                for (int ni = 0; ni < 2; ++ni) {
                    acc[mi][ni] = __builtin_amdgcn_mfma_f32_16x16x32_bf16(
                        a_h[mi], b_h[ni], acc[mi][ni], 0, 0, 0);
                    acc[mi][ni] = __builtin_amdgcn_mfma_f32_16x16x32_bf16(
                        a_h[mi], b_l[ni], acc[mi][ni], 0, 0, 0);
                    acc[mi][ni] = __builtin_amdgcn_mfma_f32_16x16x32_bf16(
                        a_l[mi], b_h[ni], acc[mi][ni], 0, 0, 0);
                }
        }
        __syncthreads();
    }

    #pragma unroll
    for (int mi = 0; mi < 2; ++mi) {
        #pragma unroll
        for (int r = 0; r < 4; ++r) {
            int row = m0 + wm + mi * 16 + quad * 4 + r;
            if (row >= Ma) continue;
            #pragma unroll
            for (int ni = 0; ni < 2; ++ni) {
                int col = n0 + wn + ni * 16 + l15;
                if (col >= HP) continue;
                size_t idx = (size_t)row * HP + col;
                float v = 0.0f;
                if (col < Nc) {
                    v = acc[mi][ni][r];
                    if constexpr (BIAS) v += bias[col];
                    if constexpr (ACT)  v = sspf(v);
                    if constexpr (ACCUM) v += unpackf(outP[idx]);
                }
                outP[idx] = packsplit(v);
            }
        }
    }
}

// Batched slab GEMM over all L layers stacked in M (1024 rows per layer).
// SHAREDA: A rows are (m % 1024). Same TK=64 structure.
template<bool SHAREDA, bool ACT>
__global__ __launch_bounds__(256, 4)
void gemm_tab(const int* __restrict__ A, int lda,
              const short* __restrict__ BhBase, const short* __restrict__ BlBase,
              int ldb, int bstride,
              const float* __restrict__ biasBase,
              int* __restrict__ outP,
              int Ma, int K, int Nc)
{
    const int NT = (Nc + TN - 1) / TN;
    const int f = blockIdx.x;
    const int xcd = f & 7, s = f >> 3;
    const int n0 = (s % NT) * TN;
    const int m0 = (xcd + 8 * (s / NT)) * TM;
    if (m0 >= Ma) return;

    const int layer = m0 >> 10;
    const int arow0 = SHAREDA ? (m0 & 1023) : m0;
    const short* __restrict__ Bh = BhBase + (size_t)layer * bstride;
    const short* __restrict__ Bl = BlBase + (size_t)layer * bstride;
    const float* __restrict__ bias = biasBase + (size_t)layer * H_DIM;

    __shared__ __align__(16) short As[2][TM * SA];
    __shared__ __align__(16) short Bs[2][TN * SA];

    const int tid = threadIdx.x;
    const int lane = tid & 63, wid = tid >> 6;
    const int wm = (wid >> 1) * 32, wn = (wid & 1) * 32;
    const int l15 = lane & 15, quad = lane >> 4;
    const int srow = tid >> 2;
    const int skk  = (tid & 3) << 4;

    const int gn = min(n0 + srow, Nc - 1);
    const int*   aPtr  = A  + (size_t)(arow0 + srow) * lda + skk;
    const short* bPtrH = Bh + (size_t)gn * ldb + skk;
    const short* bPtrL = Bl + (size_t)gn * ldb + skk;

    f32x4 acc[2][2];
    #pragma unroll
    for (int i = 0; i < 2; ++i)
        #pragma unroll
        for (int j = 0; j < 2; ++j)
            acc[i][j] = (f32x4){0.f, 0.f, 0.f, 0.f};

    int4 ra[4];
    int4 rbh0, rbh1, rbl0, rbl1;

    #pragma unroll
    for (int j = 0; j < 4; ++j) ra[j] = *(const int4*)(aPtr + 4 * j);
    rbh0 = *(const int4*)bPtrH; rbh1 = *(const int4*)(bPtrH + 8);
    rbl0 = *(const int4*)bPtrL; rbl1 = *(const int4*)(bPtrL + 8);
    aPtr += TK; bPtrH += TK; bPtrL += TK;

    for (int k0 = 0; k0 < K; k0 += TK) {
        {
            #pragma unroll
            for (int j = 0; j < 4; ++j) {
                short4 vh, vl;
                unpack4(ra[j], vh, vl);
                *(short4*)&As[0][srow * SA + skk + 4 * j] = vh;
                *(short4*)&As[1][srow * SA + skk + 4 * j] = vl;
            }
            *(int4*)&Bs[0][srow * SA + skk]     = rbh0;
            *(int4*)&Bs[0][srow * SA + skk + 8] = rbh1;
            *(int4*)&Bs[1][srow * SA + skk]     = rbl0;
            *(int4*)&Bs[1][srow * SA + skk + 8] = rbl1;
        }
        __syncthreads();

        if (k0 + TK < K) {
            #pragma unroll
            for (int j = 0; j < 4; ++j) ra[j] = *(const int4*)(aPtr + 4 * j);
            rbh0 = *(const int4*)bPtrH; rbh1 = *(const int4*)(bPtrH + 8);
            rbl0 = *(const int4*)bPtrL; rbl1 = *(const int4*)(bPtrL + 8);
            aPtr += TK; bPtrH += TK; bPtrL += TK;
        }

        #pragma unroll
        for (int kk = 0; kk < 2; ++kk) {
            bf16x8 a_h[2], a_l[2], b_h[2], b_l[2];
            #pragma unroll
            for (int mi = 0; mi < 2; ++mi) {
                int off = (wm + mi * 16 + l15) * SA + kk * 32 + quad * 8;
                a_h[mi] = *(const bf16x8*)&As[0][off];
                a_l[mi] = *(const bf16x8*)&As[1][off];
            }
            #pragma unroll
            for (int ni = 0; ni < 2; ++ni) {
                int off = (wn + ni * 16 + l15) * SA + kk * 32 + quad * 8;
                b_h[ni] = *(const bf16x8*)&Bs[0][off];
                b_l[ni] = *(const bf16x8*)&Bs[1][off];
            }
            #pragma unroll
            for (int mi = 0; mi < 2; ++mi)
                #pragma unroll
                for (int ni = 0; ni < 2; ++ni) {
                    acc[mi][ni] = __builtin_amdgcn_mfma_f32_16x16x32_bf16(
                        a_h[mi], b_h[ni], acc[mi][ni], 0, 0, 0);
                    acc[mi][ni] = __builtin_amdgcn_mfma_f32_16x16x32_bf16(
                        a_h[mi], b_l[ni], acc[mi][ni], 0, 0, 0);
                    acc[mi][ni] = __builtin_amdgcn_mfma_f32_16x16x32_bf16(
                        a_l[mi], b_h[ni], acc[mi][ni], 0, 0, 0);
                }
        }
        __syncthreads();
    }

    #pragma unroll
    for (int mi = 0; mi < 2; ++mi) {
        #pragma unroll
        for (int r = 0; r < 4; ++r) {
            int row = m0 + wm + mi * 16 + quad * 4 + r;
            if (row >= Ma) continue;
            #pragma unroll
            for (int ni = 0; ni < 2; ++ni) {
                int col = n0 + wn + ni * 16 + l15;
                if (col >= HP) continue;
                float v = 0.0f;
                if (col < Nc) {
                    v = acc[mi][ni][r] + bias[col];
                    if constexpr (ACT) v = sspf(v);
                }
                outP[(size_t)row * HP + col] = packsplit(v);
            }
        }
    }
}

static inline dim3 mfma_grid(int Ma, int Nc) {
    int MB = (Ma + TM - 1) / TM;
    int NT = (Nc + TN - 1) / TN;
    int Ys = ((MB + 7) / 8) * 8;
    return dim3(Ys * NT);
}

// ---------------------------------------------------------------- fp32 GEMM (final pool matmul only)
#define BM 64
#define BN 64
#define BK 16
template<bool BIAS>
__global__ __launch_bounds__(256)
void gemm_k(const float* __restrict__ A, int lda,
            const float* __restrict__ W,
            const float* __restrict__ bias,
            float* __restrict__ out,
            int Ma, int K, int Nc)
{
    __shared__ __align__(16) float Asd[BK][BM];
    __shared__ __align__(16) float Bsd[BK][BN];
    const int tid = threadIdx.x;
    const int tx = tid & 15, ty = tid >> 4;
    const int m0 = blockIdx.y * BM, n0 = blockIdx.x * BN;
    const int ar = tid >> 2, ac = (tid & 3) << 2;
    const int br = tid >> 4, bc = (tid & 15) << 2;
    float acc[4][4] = {};
    for (int k0 = 0; k0 < K; k0 += BK) {
        {
            int row = m0 + ar, col = k0 + ac;
            float4 v = make_float4(0.f, 0.f, 0.f, 0.f);
            if (row < Ma) {
                const float* ap = A + (size_t)row * lda + col;
                if (col + 3 < K) v = *(const float4*)ap;
                else {
                    if (col + 0 < K) v.x = ap[0];
                    if (col + 1 < K) v.y = ap[1];
                    if (col + 2 < K) v.z = ap[2];
                }
            }
            Asd[ac + 0][ar] = v.x; Asd[ac + 1][ar] = v.y;
            Asd[ac + 2][ar] = v.z; Asd[ac + 3][ar] = v.w;
        }
        {
            int row = k0 + br, col = n0 + bc;
            float4 v = make_float4(0.f, 0.f, 0.f, 0.f);
            if (row < K && col + 3 < Nc)
                v = *(const float4*)(W + (size_t)row * Nc + col);
            *(float4*)&Bsd[br][bc] = v;
        }
        __syncthreads();
        #pragma unroll
        for (int kk = 0; kk < BK; ++kk) {
            float4 a4 = *(const float4*)&Asd[kk][ty << 2];
            float4 b4 = *(const float4*)&Bsd[kk][tx << 2];
            float av[4] = {a4.x, a4.y, a4.z, a4.w};
            float bv[4] = {b4.x, b4.y, b4.z, b4.w};
            #pragma unroll
            for (int i = 0; i < 4; ++i)
                #pragma unroll
                for (int j = 0; j < 4; ++j)
                    acc[i][j] = fmaf(av[i], bv[j], acc[i][j]);
        }
        __syncthreads();
    }
    #pragma unroll
    for (int i = 0; i < 4; ++i) {
        int row = m0 + (ty << 2) + i;
        if (row >= Ma) continue;
        #pragma unroll
        for (int j = 0; j < 4; ++j) {
            int col = n0 + (tx << 2) + j;
            if (col >= Nc) continue;
            float v = acc[i][j];
            if constexpr (BIAS) v += bias[col];
            out[(size_t)row * Nc + col] = v;
        }
    }
}

// ---------------------------------------------------------------- weight prep
__global__ __launch_bounds__(256)
void wts_w1_k(const float* __restrict__ w_all, short* __restrict__ oh,
              short* __restrict__ ol)
{
    __shared__ short th[64][65], tl[64][65];
    const int layer = blockIdx.z;
    const float* w = w_all + (size_t)layer * G_DIM * H_DIM;
    short* ohz = oh + (size_t)layer * H_DIM * 64;
    short* olz = ol + (size_t)layer * H_DIM * 64;
    const int n0 = blockIdx.y * 64;
    const int tid = threadIdx.x;
    #pragma unroll
    for (int p = 0; p < 4; ++p) {
        int k = p * 16 + (tid >> 4);
        int n4 = (tid & 15) << 2;
        float4 v = make_float4(0.f, 0.f, 0.f, 0.f);
        if (k < G_DIM && n0 + n4 + 3 < H_DIM)
            v = *(const float4*)(w + (size_t)k * H_DIM + n0 + n4);
        int px = packsplit(v.x), py = packsplit(v.y);
        int pz = packsplit(v.z), pw = packsplit(v.w);
        th[n4 + 0][k] = (short)(px >> 16); tl[n4 + 0][k] = (short)px;
        th[n4 + 1][k] = (short)(py >> 16); tl[n4 + 1][k] = (short)py;
        th[n4 + 2][k] = (short)(pz >> 16); tl[n4 + 2][k] = (short)pz;
        th[n4 + 3][k] = (short)(pw >> 16); tl[n4 + 3][k] = (short)pw;
    }
    __syncthreads();
    #pragma unroll
    for (int p = 0; p < 4; ++p) {
        int n = p * 16 + (tid >> 4);
        int k4 = (tid & 15) << 2;
        if (n0 + n >= H_DIM) continue;
        short4 sh = { th[n][k4], th[n][k4 + 1], th[n][k4 + 2], th[n][k4 + 3] };
        short4 sl = { tl[n][k4], tl[n][k4 + 1], tl[n][k4 + 2], tl[n][k4 + 3] };
        *(short4*)(ohz + (size_t)(n0 + n) * 64 + k4) = sh;
        *(short4*)(olz + (size_t)(n0 + n) * 64 + k4) = sl;
    }
}

// big weights [600][600] -> hi/lo [600][HP] (k zero-padded 600..639)
__global__ __launch_bounds__(256)
void wts_big_k(const float* __restrict__ w2, const float* __restrict__ l1,
               const float* __restrict__ l2, const float* __restrict__ iw,
               short* __restrict__ oh2, short* __restrict__ ol2,
               short* __restrict__ oh1, short* __restrict__ ol1,
               short* __restrict__ ohl2, short* __restrict__ oll2,
               short* __restrict__ ohi, short* __restrict__ oli)
{
    __shared__ short th[64][65], tl[64][65];
    const int z = blockIdx.z, type = z / L_LAYERS, layer = z % L_LAYERS;
    const float* w; short* oh; short* ol;
    if (type == 0)      { w = w2; oh = oh2; ol = ol2; }
    else if (type == 1) { w = l1; oh = oh1; ol = ol1; }
    else if (type == 2) { w = l2; oh = ohl2; ol = oll2; }
    else                { w = iw; oh = ohi; ol = oli; }
    w  += (size_t)layer * H_DIM * H_DIM;
    oh += (size_t)layer * H_DIM * HP;
    ol += (size_t)layer * H_DIM * HP;
    const int k0 = blockIdx.x * 64, n0 = blockIdx.y * 64;
    const int tid = threadIdx.x;
    #pragma unroll
    for (int p = 0; p < 4; ++p) {
        int k = p * 16 + (tid >> 4);
        int n4 = (tid & 15) << 2;
        float4 v = make_float4(0.f, 0.f, 0.f, 0.f);
        if (k0 + k < H_DIM && n0 + n4 + 3 < H_DIM)
            v = *(const float4*)(w + (size_t)(k0 + k) * H_DIM + n0 + n4);
        int px = packsplit(v.x), py = packsplit(v.y);
        int pz = packsplit(v.z), pw = packsplit(v.w);
        th[n4 + 0][k] = (short)(px >> 16); tl[n4 + 0][k] = (short)px;
        th[n4 + 1][k] = (short)(py >> 16); tl[n4 + 1][k] = (short)py;
        th[n4 + 2][k] = (short)(pz >> 16); tl[n4 + 2][k] = (short)pz;
        th[n4 + 3][k] = (short)(pw >> 16); tl[n4 + 3][k] = (short)pw;
    }
    __syncthreads();
    #pragma unroll
    for (int p = 0; p < 4; ++p) {
        int n = p * 16 + (tid >> 4);
        int k4 = (tid & 15) << 2;
        if (n0 + n >= H_DIM || k0 + k4 > HP - 4) continue;
        short4 sh = { th[n][k4], th[n][k4 + 1], th[n][k4 + 2], th[n][k4 + 3] };
        short4 sl = { tl[n][k4], tl[n][k4 + 1], tl[n][k4 + 2], tl[n][k4 + 3] };
        *(short4*)(oh + (size_t)(n0 + n) * HP + k0 + k4) = sh;
        *(short4*)(ol + (size_t)(n0 + n) * HP + k0 + k4) = sl;
    }
}

// ---------------------------------------------------------------- helpers
__global__ __launch_bounds__(256)
void init_h_k(const int* __restrict__ z, const float* __restrict__ emb,
              int* __restrict__ hP)
{
    int t = blockIdx.x * 256 + threadIdx.x;
    const int QC = HP / 4;   // 160
    if (t >= N_ATOMS * QC) return;
    int i = t / QC;
    int q = (t - i * QC) << 2;
    size_t idx = (size_t)i * HP + q;
    if (q < H_DIM) {
        float4 v = *(const float4*)(emb + (size_t)z[i] * H_DIM + q);
        *(int4*)(hP + idx) = make_int4(packsplit(v.x), packsplit(v.y),
                                       packsplit(v.z), packsplit(v.w));
    } else {
        *(int4*)(hP + idx) = make_int4(0, 0, 0, 0);
    }
}

// per-edge record: {src*HP, i0*HP, a = C - f*C, b = f*C}
__global__ __launch_bounds__(256)
void edge_geom_k(const float* __restrict__ pos, const int* __restrict__ src,
                 const int* __restrict__ dst, float4* __restrict__ einfo)
{
    int e = blockIdx.x * 256 + threadIdx.x;
    if (e >= E_EDGES) return;
    int s = src[e], d0 = dst[e];
    float dx = pos[s * 3 + 0] - pos[d0 * 3 + 0];
    float dy = pos[s * 3 + 1] - pos[d0 * 3 + 1];
    float dz = pos[s * 3 + 2] - pos[d0 * 3 + 2];
    float dist = sqrtf(dx * dx + dy * dy + dz * dz + 1e-12f);
    float cc = 0.5f * (cosf(dist * 0.31415926535f) + 1.0f);
    float u = dist * ((float)(M_TAB - 1) / DMAX);
    u = fminf(fmaxf(u, 0.0f), (float)(M_TAB - 1) - 0.001f);
    int i0 = (int)u;
    float fc = (u - (float)i0) * cc;
    einfo[e] = make_float4(__int_as_float(s * HP),
                           __int_as_float(i0 * HP),
                           cc - fc, fc);
}

__global__ __launch_bounds__(256)
void rbf_tab_k(int* __restrict__ rtabP)
{
    int t = blockIdx.x * 256 + threadIdx.x;
    if (t >= M_TAB * 64) return;
    int i = t >> 6, g = t & 63;
    float v = 0.0f;
    if (g < G_DIM) {
        float dg  = (float)i * (DMAX / (float)(M_TAB - 1));
        float off = (float)g * (10.0f / 49.0f);
        float x = dg - off;
        const float coeff = -0.5f * (49.0f / 10.0f) * (49.0f / 10.0f);
        v = expf(coeff * x * x);
    }
    rtabP[t] = packsplit(v);
}

// ---------------------------------------------------------------- CSR build
__global__ __launch_bounds__(256)
void hist_k(const int* __restrict__ dst, int* __restrict__ deg)
{
    int e = blockIdx.x * 256 + threadIdx.x;
    if (e >= E_EDGES) return;
    atomicAdd(&deg[dst[e]], 1);
}

__global__ __launch_bounds__(1024)
void scan_k(const int* __restrict__ deg, int* __restrict__ rowptr)
{
    __shared__ int sums[1024];
    int tid = threadIdx.x;
    const int CHUNK = (N_ATOMS + 1023) / 1024;
    int base = tid * CHUNK;
    int local[16];
    int s = 0;
    #pragma unroll
    for (int c = 0; c < 16; ++c) {
        if (c >= CHUNK) break;
        int idx = base + c;
        local[c] = s;
        s += (idx < N_ATOMS) ? deg[idx] : 0;
    }
    sums[tid] = s;
    __syncthreads();
    for (int off = 1; off < 1024; off <<= 1) {
        int v = (tid >= off) ? sums[tid - off] : 0;
        __syncthreads();
        sums[tid] += v;
        __syncthreads();
    }
    int prefix = (tid > 0) ? sums[tid - 1] : 0;
    #pragma unroll
    for (int c = 0; c < 16; ++c) {
        if (c >= CHUNK) break;
        int idx = base + c;
        if (idx <= N_ATOMS) rowptr[idx] = prefix + local[c];
    }
    if (tid == 1023) rowptr[N_ATOMS] = sums[1023];
}

__global__ __launch_bounds__(256)
void fill_k(const int* __restrict__ dst, const float4* __restrict__ einfo,
            const int* __restrict__ rowptr, int* __restrict__ cursor,
            float4* __restrict__ esorted)
{
    int e = blockIdx.x * 256 + threadIdx.x;
    if (e >= E_EDGES) return;
    int d0 = dst[e];
    int pos = rowptr[d0] + atomicAdd(&cursor[d0], 1);
    esorted[pos] = einfo[e];
}

// molecule boundaries via binary search over the SORTED batch array
__global__ __launch_bounds__(256)
void bounds_k(const int* __restrict__ batch, int* __restrict__ mrow)
{
    int b = threadIdx.x;
    if (b > B_MOLS) return;
    int lo = 0, hi = N_ATOMS;
    while (lo < hi) {
        int mid = (lo + hi) >> 1;
        if (batch[mid] < b) lo = mid + 1; else hi = mid;
    }
    mrow[b] = lo;
}

// ---------------------------------------------------------------- gather
__device__ __forceinline__ void gacc(float4& acc, const int* yP, const int* wtP,
                                     const float4& ei, int q)
{
    int srow = __float_as_int(ei.x);
    int wrow = __float_as_int(ei.y);
    float a = ei.z, b = ei.w;
    int4 yv = *(const int4*)(yP + srow + q);
    int4 w0 = *(const int4*)(wtP + wrow + q);
    int4 w1 = *(const int4*)(wtP + wrow + HP + q);
    acc.x += unpackf(yv.x) * (a * unpackf(w0.x) + b * unpackf(w1.x));
    acc.y += unpackf(yv.y) * (a * unpackf(w0.y) + b * unpackf(w1.y));
    acc.z += unpackf(yv.z) * (a * unpackf(w0.z) + b * unpackf(w1.z));
    acc.w += unpackf(yv.w) * (a * unpackf(w0.w) + b * unpackf(w1.w));
}

__global__ __launch_bounds__(256)
void gather_k(const int* __restrict__ yP, const int* __restrict__ wtP,
              const int* __restrict__ rowptr, const float4* __restrict__ esorted,
              int* __restrict__ aggP)
{
    int t = blockIdx.x * 256 + threadIdx.x;
    const int QC = HP / 4;   // 160
    if (t >= N_ATOMS * QC) return;
    int i = t / QC;
    int q = (t - i * QC) << 2;
    size_t idx = (size_t)i * HP + q;
    if (q >= H_DIM) { *(int4*)(aggP + idx) = make_int4(0, 0, 0, 0); return; }
    int j0 = rowptr[i], j1 = rowptr[i + 1];
    float4 a0 = make_float4(0.f, 0.f, 0.f, 0.f);
    float4 a1 = make_float4(0.f, 0.f, 0.f, 0.f);
    int j = j0;
    for (; j + 2 <= j1; j += 2) {
        float4 e0 = esorted[j], e1 = esorted[j + 1];
        gacc(a0, yP, wtP, e0, q);
        gacc(a1, yP, wtP, e1, q);
    }
    if (j < j1) gacc(a0, yP, wtP, esorted[j], q);
    a0.x += a1.x; a0.y += a1.y; a0.z += a1.z; a0.w += a1.w;
    *(int4*)(aggP + idx) = make_int4(packsplit(a0.x), packsplit(a0.y),
                                     packsplit(a0.z), packsplit(a0.w));
}

// ---------------------------------------------------------------- pool (segment mean, no atomics)
__global__ __launch_bounds__(256)
void pool_seg_k(const int* __restrict__ hP, const int* __restrict__ mrow,
                float* __restrict__ pooled)
{
    int b = blockIdx.x;
    int t = threadIdx.x;
    if (t >= 150) return;               // cols 600..639 are pad
    int q = t << 2;
    int a = mrow[b], a1 = mrow[b + 1];
    float cnt = (float)(a1 - a);
    float4 s0 = make_float4(0.f, 0.f, 0.f, 0.f);
    float4 s1 = make_float4(0.f, 0.f, 0.f, 0.f);
    for (; a + 2 <= a1; a += 2) {
        int4 p0 = *(const int4*)(hP + (size_t)a * HP + q);
        int4 p1 = *(const int4*)(hP + (size_t)(a + 1) * HP + q);
        s0.x += unpackf(p0.x); s0.y += unpackf(p0.y);
        s0.z += unpackf(p0.z); s0.w += unpackf(p0.w);
        s1.x += unpackf(p1.x); s1.y += unpackf(p1.y);
        s1.z += unpackf(p1.z); s1.w += unpackf(p1.w);
    }
    if (a < a1) {
        int4 p0 = *(const int4*)(hP + (size_t)a * HP + q);
        s0.x += unpackf(p0.x); s0.y += unpackf(p0.y);
        s0.z += unpackf(p0.z); s0.w += unpackf(p0.w);
    }
    float inv = 1.0f / fmaxf(cnt, 1.0f);
    float4 o = make_float4((s0.x + s1.x) * inv, (s0.y + s1.y) * inv,
                           (s0.z + s1.z) * inv, (s0.w + s1.w) * inv);
    *(float4*)(pooled + (size_t)b * H_DIM + q) = o;
}

// ---------------------------------------------------------------- launch
extern "C" void kernel_launch(void* const* d_in, const int* in_sizes, int n_in,
                              void* d_out, int out_size, void* d_ws, size_t ws_size,
                              hipStream_t stream)
{
    const int*   z      = (const int*)  d_in[0];
    const float* pos    = (const float*)d_in[1];
    const int*   batch  = (const int*)  d_in[2];
    const int*   eidx   = (const int*)  d_in[3];
    const float* emb    = (const float*)d_in[4];
    const float* mlp_w1 = (const float*)d_in[5];
    const float* mlp_b1 = (const float*)d_in[6];
    const float* mlp_w2 = (const float*)d_in[7];
    const float* mlp_b2 = (const float*)d_in[8];
    const float* lin1_w = (const float*)d_in[9];
    const float* lin2_w = (const float*)d_in[10];
    const float* lin2_b = (const float*)d_in[11];
    const float* intw   = (const float*)d_in[12];
    const float* intb   = (const float*)d_in[13];
    const float* poolw  = (const float*)d_in[14];
    const float* poolb  = (const float*)d_in[15];

    float* ws = (float*)d_ws;
    const size_t NHP = (size_t)N_ATOMS * HP;       // 6,400,000
    const size_t TABALL = (size_t)L_LAYERS * M_TAB * HP;   // 3,932,160
    const size_t WTPLANE = 230400 + (size_t)4 * 6 * 600 * HP;  // 9,446,400 shorts

    int*   hP    = (int*)ws;                       // NHP
    int*   y1P   = (int*)(ws + NHP);               // NHP; aliases tP, ttabA
    int*   tP    = y1P;
    int*   ttabA = y1P;                            // prep-time alias (3.93M <= NHP)
    int*   aggP  = (int*)(ws + 2 * NHP);           // NHP
    // aggP region aliases — ONLY prep-phase data dead before gather:
    float4* einfo  = (float4*)aggP;                          // 256,000 f
    int*    deg    = (int*)((float*)aggP + 300000);          // 10,000
    int*    cursor = (int*)((float*)aggP + 310000);          // 10,000
    int*   wtabA = (int*)(ws + 3 * NHP);           // TABALL (persistent)
    int*   rtabP = (int*)(ws + 3 * NHP + TABALL);  // M_TAB*64 = 65,536
    short* wtH   = (short*)(ws + 3 * NHP + TABALL + (size_t)M_TAB * 64);
    short* wtL   = wtH + WTPLANE;
    // persistent tail (NOT aliased): esorted, pooled, rowptr, mrow
    float*  tailF   = (float*)(wtL + WTPLANE);
    float4* esorted = (float4*)tailF;                        // 256,000 f
    float*  pooled  = tailF + 256000;                        // 76,800 f
    int*    rowptr  = (int*)(tailF + 332800);                // 10,001
    int*    mrow    = rowptr + 10001;                        // 129
    // total ~33.0M 4B units = 132 MB (prior rounds used up to 144 MB OK)

    short* w1t_h = wtH;                       short* w1t_l = wtL;
    short* w2t_h = wtH + 230400;              short* w2t_l = wtL + 230400;
    short* l1t_h = w2t_h + 6 * 600 * HP;      short* l1t_l = w2t_l + 6 * 600 * HP;
    short* l2t_h = l1t_h + 6 * 600 * HP;      short* l2t_l = l1t_l + 6 * 600 * HP;
    short* int_h = l2t_h + 6 * 600 * HP;      short* int_l = l2t_l + 6 * 600 * HP;

    const int* src = eidx;
    const int* dst = eidx + E_EDGES;

    const dim3 blk(256);
    const int QC = HP / 4;
    const dim3 gN   = mfma_grid(N_ATOMS, H_DIM);            // 1600
    const dim3 gTab = mfma_grid(L_LAYERS * M_TAB, H_DIM);   // 960

    // ---- one-time prep (einfo/deg/cursor alias aggP: dead before gather)
    edge_geom_k<<<(E_EDGES + 255) / 256, blk, 0, stream>>>(pos, src, dst, einfo);
    hipMemsetAsync(deg, 0, 2 * N_ATOMS * sizeof(int), stream);
    hist_k <<<(E_EDGES + 255) / 256, blk, 0, stream>>>(dst, deg);
    scan_k <<<1, 1024, 0, stream>>>(deg, rowptr);
    fill_k <<<(E_EDGES + 255) / 256, blk, 0, stream>>>(dst, einfo, rowptr, cursor, esorted);
    bounds_k <<<1, 256, 0, stream>>>(batch, mrow);
    init_h_k <<<(N_ATOMS * QC + 255) / 256, blk, 0, stream>>>(z, emb, hP);
    rbf_tab_k<<<(M_TAB * 64 + 255) / 256,   blk, 0, stream>>>(rtabP);
    wts_w1_k  <<<dim3(1, 10, 6),   blk, 0, stream>>>(mlp_w1, w1t_h, w1t_l);
    wts_big_k <<<dim3(10, 10, 24), blk, 0, stream>>>(
        mlp_w2, lin1_w, lin2_w, intw,
        w2t_h, w2t_l, l1t_h, l1t_l, l2t_h, l2t_l, int_h, int_l);

    // ---- all 6 layers' filter tables in 2 batched slab GEMMs
    gemm_tab<true, true><<<gTab, blk, 0, stream>>>(
        rtabP, 64, w1t_h, w1t_l, 64, 600 * 64, mlp_b1,
        ttabA, L_LAYERS * M_TAB, 64, H_DIM);
    gemm_tab<false, false><<<gTab, blk, 0, stream>>>(
        ttabA, HP, w2t_h, w2t_l, HP, 600 * HP, mlp_b2,
        wtabA, L_LAYERS * M_TAB, HP, H_DIM);

    for (int k = 0; k < L_LAYERS; ++k) {
        const float* l2b = lin2_b + (size_t)k * H_DIM;
        const float* ib  = intb   + (size_t)k * H_DIM;
        const short* l1h = l1t_h + (size_t)k * H_DIM * HP;
        const short* l1l = l1t_l + (size_t)k * H_DIM * HP;
        const short* l2h = l2t_h + (size_t)k * H_DIM * HP;
        const short* l2l = l2t_l + (size_t)k * H_DIM * HP;
        const short* ih  = int_h + (size_t)k * H_DIM * HP;
        const short* il  = int_l + (size_t)k * H_DIM * HP;
        const int*   wtP = wtabA + (size_t)k * M_TAB * HP;

        // y1P = packsplit(h @ lin1)
        gemm_mfma<false, false, false><<<gN, blk, 0, stream>>>(
            hP, HP, l1h, l1l, HP, nullptr, y1P, N_ATOMS, HP, H_DIM);
        // aggP = packsplit(CSR-gather(y1 * W(d) * C))
        gather_k<<<(N_ATOMS * QC + 255) / 256, blk, 0, stream>>>(
            y1P, wtP, rowptr, esorted, aggP);
        // tP = packsplit(ssp(agg @ lin2 + b))   (aliases y1P)
        gemm_mfma<true, true, false><<<gN, blk, 0, stream>>>(
            aggP, HP, l2h, l2l, HP, l2b, tP, N_ATOMS, HP, H_DIM);
        // hP = packsplit(unpack(hP) + t @ int_w + ib)
        gemm_mfma<true, false, true><<<gN, blk, 0, stream>>>(
            tP, HP, ih, il, HP, ib, hP, N_ATOMS, HP, H_DIM);
    }

    // segment-mean pool (sorted batch, no atomics), then out = pooled @ pool_w + b
    pool_seg_k<<<B_MOLS, blk, 0, stream>>>(hP, mrow, pooled);
    gemm_k<true><<<dim3((H_DIM + BN - 1) / BN, (B_MOLS + BM - 1) / BM), blk, 0, stream>>>(
        pooled, H_DIM, poolw, poolb, (float*)d_out, B_MOLS, H_DIM, H_DIM);
}